// Round 2
// baseline (11083.029 us; speedup 1.0000x reference)
//
#include <hip/hip_runtime.h>
#include <hip/hip_bf16.h>
#include <math.h>

#define B_    32
#define DIM_  384
#define HID_  1536
#define P_    196     // 14*14 tokens
#define T_    6272    // B_*P_
#define NC_   1000
#define KSTEM_ 768    // 3*16*16
#define DEPTH_ 18
#define SCALE_ 0.05103103630798288f  // 384^-0.5

enum { EPI_NONE = 0, EPI_BIAS = 1, EPI_BIAS_GELU = 2, EPI_BIAS_ACC = 3 };

__device__ __forceinline__ float gelu_exact(float v) {
  return 0.5f * v * (1.0f + erff(v * 0.70710678118654752f));
}

// ---------------------------------------------------------------------------
// Templated fp32 GEMM: C = A(MxK) @ B(KxN) [+bias][+gelu][+accum]
// BM x BN tile, 256 threads (16x16), TM x TN = BM/16 x BN/16 microtile,
// k-step 16, register prefetch of next k-tile.
// grid = (N/BN, M/BM). K must be a multiple of 16.
// ---------------------------------------------------------------------------
template <int BM, int BN, int EPI>
__global__ __launch_bounds__(256) void gemmT(
    const float* __restrict__ A, const float* __restrict__ Bm,
    float* __restrict__ C, const float* __restrict__ bias,
    int M, int N, int K)
{
  constexpr int TM = BM / 16, TN = BN / 16;
  // +4 pad keeps row stride a multiple of 16B and breaks power-of-2 strides
  __shared__ float As[16][BM + 4];   // [k][m] transposed
  __shared__ float Bs[16][BN + 4];   // [k][n]

  const int tx = threadIdx.x, ty = threadIdx.y;
  const int tid = ty * 16 + tx;
  const int m0 = blockIdx.y * BM, n0 = blockIdx.x * BN;

  const int arow = (BM == 128) ? (tid >> 1) : (tid >> 2);
  const int akq  = (BM == 128) ? ((tid & 1) * 8) : ((tid & 3) * 4);
  const int brow = tid >> 4;          // 0..15
  const int bc0  = (tid & 15) * 4;    // 0..60

  const float* Aptr = A + (size_t)(m0 + arow) * K + akq;
  const float* Bptr = Bm + (size_t)brow * N + n0 + bc0;

  float4 pa[(BM == 128) ? 2 : 1];
  float4 pb[(BN == 128) ? 2 : 1];

  auto loadTile = [&](int kt, float4* ra, float4* rb) {
    ra[0] = *(const float4*)&Aptr[kt];
    if constexpr (BM == 128) ra[1] = *(const float4*)&Aptr[kt + 4];
    rb[0] = *(const float4*)&Bptr[(size_t)kt * N];
    if constexpr (BN == 128) rb[1] = *(const float4*)&Bptr[(size_t)kt * N + 64];
  };
  auto storeTile = [&](const float4* ra, const float4* rb) {
    As[akq + 0][arow] = ra[0].x;
    As[akq + 1][arow] = ra[0].y;
    As[akq + 2][arow] = ra[0].z;
    As[akq + 3][arow] = ra[0].w;
    if constexpr (BM == 128) {
      As[akq + 4][arow] = ra[1].x;
      As[akq + 5][arow] = ra[1].y;
      As[akq + 6][arow] = ra[1].z;
      As[akq + 7][arow] = ra[1].w;
    }
    *(float4*)&Bs[brow][bc0] = rb[0];
    if constexpr (BN == 128) *(float4*)&Bs[brow][bc0 + 64] = rb[1];
  };

  float acc[TM][TN] = {};

  loadTile(0, pa, pb);
  for (int kt = 0; kt < K; kt += 16) {
    storeTile(pa, pb);
    __syncthreads();
    const bool more = (kt + 16) < K;
    if (more) loadTile(kt + 16, pa, pb);   // prefetch next tile into regs
#pragma unroll
    for (int kk = 0; kk < 16; ++kk) {
      float a[TM], b[TN];
#pragma unroll
      for (int i = 0; i < TM; i += 4)
        *(float4*)&a[i] = *(const float4*)&As[kk][ty * TM + i];
#pragma unroll
      for (int j = 0; j < TN; j += 4)
        *(float4*)&b[j] = *(const float4*)&Bs[kk][tx * TN + j];
#pragma unroll
      for (int i = 0; i < TM; ++i)
#pragma unroll
        for (int j = 0; j < TN; ++j)
          acc[i][j] = fmaf(a[i], b[j], acc[i][j]);
    }
    __syncthreads();
  }

  float bsv[TN];
  if (EPI != EPI_NONE) {
#pragma unroll
    for (int j = 0; j < TN; j += 4)
      *(float4*)&bsv[j] = *(const float4*)&bias[n0 + tx * TN + j];
  }
#pragma unroll
  for (int i = 0; i < TM; ++i) {
    float* crow = &C[(size_t)(m0 + ty * TM + i) * N + n0 + tx * TN];
#pragma unroll
    for (int j = 0; j < TN; j += 4) {
      float4 v;
      v.x = acc[i][j];
      v.y = acc[i][j + 1];
      v.z = acc[i][j + 2];
      v.w = acc[i][j + 3];
      if (EPI == EPI_BIAS) {
        v.x += bsv[j]; v.y += bsv[j + 1]; v.z += bsv[j + 2]; v.w += bsv[j + 3];
      } else if (EPI == EPI_BIAS_GELU) {
        v.x = gelu_exact(v.x + bsv[j]);
        v.y = gelu_exact(v.y + bsv[j + 1]);
        v.z = gelu_exact(v.z + bsv[j + 2]);
        v.w = gelu_exact(v.w + bsv[j + 3]);
      } else if (EPI == EPI_BIAS_ACC) {
        float4 c = *(const float4*)&crow[j];
        v.x += c.x + bsv[j]; v.y += c.y + bsv[j + 1];
        v.z += c.z + bsv[j + 2]; v.w += c.w + bsv[j + 3];
      }
      *(float4*)&crow[j] = v;
    }
  }
}

// ---------------------------------------------------------------------------
// im2col for the 16x16/stride16 stem: patches (T_, 768)
// ---------------------------------------------------------------------------
__global__ void im2col_stem(const float* __restrict__ x, float* __restrict__ patch)
{
  const int idx = blockIdx.x * 256 + threadIdx.x;
  if (idx >= T_ * KSTEM_) return;
  const int row = idx / KSTEM_;
  const int k   = idx % KSTEM_;
  const int b   = row / P_;
  const int pix = row % P_;
  const int py = pix / 14, px = pix % 14;
  const int c  = k >> 8;          // 0..2
  const int r  = k & 255;
  const int iy = r >> 4, ix = r & 15;
  patch[idx] = x[((size_t)b * 3 + c) * 50176 + (size_t)(py * 16 + iy) * 224 + (px * 16 + ix)];
}

// stem_w is (384, 768) = (N, K); GEMM wants (K, N)
__global__ void transpose_stem(const float* __restrict__ sw, float* __restrict__ out)
{
  const int idx = blockIdx.x * 256 + threadIdx.x;
  if (idx >= DIM_ * KSTEM_) return;
  const int co = idx / KSTEM_, k = idx % KSTEM_;
  out[(size_t)k * DIM_ + co] = sw[idx];
}

__global__ void lat_init(const float* __restrict__ latent, float* __restrict__ lat)
{
  const int idx = blockIdx.x * 256 + threadIdx.x;
  if (idx < B_ * DIM_) lat[idx] = latent[idx % DIM_];
}

// ---------------------------------------------------------------------------
// Readout body (384 threads): q = lat@q_w; s = q.k * SCALE; softmax; o = a.v;
// lat = LN(lat + o@out_w + out_b, eps=1e-5). kv is (b,t,768), k=[0:384) v=[384:768).
// ---------------------------------------------------------------------------
__device__ __forceinline__ void readout_body(
    int b, const float* __restrict__ kv, float* __restrict__ lat,
    const float* __restrict__ q_w, const float* __restrict__ out_w,
    const float* __restrict__ out_b, const float* __restrict__ lng,
    const float* __restrict__ lnb)
{
  const int tid = threadIdx.x;   // 0..383
  __shared__ float latS[DIM_], qS[DIM_], oS[DIM_], tS[DIM_];
  __shared__ float aS[P_];
  __shared__ float sS[256];
  __shared__ float redR[6], statR[2];

  latS[tid] = lat[b * DIM_ + tid];
  __syncthreads();

  // q = lat @ q_w   (one output per thread, coalesced weight reads)
  {
    float acc = 0.f;
    for (int d = 0; d < DIM_; ++d) acc = fmaf(latS[d], q_w[d * DIM_ + tid], acc);
    qS[tid] = acc;
  }
  __syncthreads();

  // scores (one token per thread for tid < P_)
  float my_s = -3.4e38f;
  if (tid < P_) {
    const float* kr = kv + ((size_t)(b * P_ + tid)) * 768;
    float acc = 0.f;
    for (int d = 0; d < DIM_; ++d) acc = fmaf(qS[d], kr[d], acc);
    my_s = acc * SCALE_;
  }
  if (tid < 256) sS[tid] = my_s;
  __syncthreads();
  for (int off = 128; off > 0; off >>= 1) {
    if (tid < off) sS[tid] = fmaxf(sS[tid], sS[tid + off]);
    __syncthreads();
  }
  const float mx = sS[0];
  __syncthreads();
  const float ex = (tid < P_) ? expf(my_s - mx) : 0.f;
  if (tid < 256) sS[tid] = ex;
  __syncthreads();
  for (int off = 128; off > 0; off >>= 1) {
    if (tid < off) sS[tid] += sS[tid + off];
    __syncthreads();
  }
  const float den = sS[0];
  if (tid < P_) aS[tid] = ex / den;
  __syncthreads();

  // o = a @ v   (one channel per thread, coalesced v reads)
  {
    float acc = 0.f;
    for (int t = 0; t < P_; ++t)
      acc = fmaf(aS[t], kv[((size_t)(b * P_ + t)) * 768 + DIM_ + tid], acc);
    oS[tid] = acc;
  }
  __syncthreads();

  // out proj + residual
  {
    float acc = out_b[tid] + latS[tid];
    for (int d = 0; d < DIM_; ++d) acc = fmaf(oS[d], out_w[d * DIM_ + tid], acc);
    tS[tid] = acc;
  }
  __syncthreads();

  // LayerNorm (eps 1e-5), 6-wave shuffle reduce
  const int lane = tid & 63, wv = tid >> 6;
  const float val = tS[tid];
  float s = val;
#pragma unroll
  for (int off = 32; off > 0; off >>= 1) s += __shfl_down(s, off);
  if (lane == 0) redR[wv] = s;
  __syncthreads();
  if (tid == 0) {
    float t = 0.f;
    for (int i = 0; i < 6; ++i) t += redR[i];
    statR[0] = t * (1.0f / DIM_);
  }
  __syncthreads();
  const float mu = statR[0];
  const float dv = val - mu;
  s = dv * dv;
#pragma unroll
  for (int off = 32; off > 0; off >>= 1) s += __shfl_down(s, off);
  if (lane == 0) redR[wv] = s;
  __syncthreads();
  if (tid == 0) {
    float t = 0.f;
    for (int i = 0; i < 6; ++i) t += redR[i];
    statR[1] = t * (1.0f / DIM_);
  }
  __syncthreads();
  const float inv = 1.0f / sqrtf(statR[1] + 1e-5f);
  lat[b * DIM_ + tid] = dv * inv * lng[tid] + lnb[tid];
}

// ---------------------------------------------------------------------------
// Fused kernel: blocks [0,B_) do the readout for the CURRENT h (kv already
// computed into kvb); blocks [B_, B_+T_) do depthwise 7x7 conv + LN for the
// next layer. The two are data-independent. Readout blocks first so they
// start immediately and hide under the conv.
// ---------------------------------------------------------------------------
__global__ __launch_bounds__(384) void dwconv_readout(
    const float* __restrict__ h, const float* __restrict__ w,
    const float* __restrict__ wb, const float* __restrict__ g,
    const float* __restrict__ beta, float* __restrict__ y,
    const float* __restrict__ kv, float* __restrict__ lat,
    const float* __restrict__ q_w, const float* __restrict__ out_w,
    const float* __restrict__ out_b, const float* __restrict__ lng,
    const float* __restrict__ lnb)
{
  if (blockIdx.x < B_) {
    readout_body(blockIdx.x, kv, lat, q_w, out_w, out_b, lng, lnb);
    return;
  }
  const int c = threadIdx.x;
  const int p = blockIdx.x - B_;
  const int b = p / P_, pix = p % P_;
  const int py = pix / 14, px = pix % 14;
  const float* hb = h + (size_t)b * P_ * DIM_;

  float acc = wb[c];
  const float* wr = w + c * 49;
#pragma unroll
  for (int ky = 0; ky < 7; ++ky) {
    const int qy = py + ky - 3;
    if ((unsigned)qy >= 14u) continue;
#pragma unroll
    for (int kx = 0; kx < 7; ++kx) {
      const int qx = px + kx - 3;
      if ((unsigned)qx >= 14u) continue;
      acc = fmaf(hb[(size_t)(qy * 14 + qx) * DIM_ + c], wr[ky * 7 + kx], acc);
    }
  }

  // LayerNorm over the 384 channels of this token (eps 1e-6)
  __shared__ float red[6];
  __shared__ float stat[2];
  const int lane = c & 63, wv = c >> 6;

  float s = acc;
#pragma unroll
  for (int off = 32; off > 0; off >>= 1) s += __shfl_down(s, off);
  if (lane == 0) red[wv] = s;
  __syncthreads();
  if (c == 0) {
    float t = 0.f;
    for (int i = 0; i < 6; ++i) t += red[i];
    stat[0] = t * (1.0f / DIM_);
  }
  __syncthreads();
  const float mu = stat[0];
  const float d = acc - mu;
  s = d * d;
#pragma unroll
  for (int off = 32; off > 0; off >>= 1) s += __shfl_down(s, off);
  if (lane == 0) red[wv] = s;
  __syncthreads();
  if (c == 0) {
    float t = 0.f;
    for (int i = 0; i < 6; ++i) t += red[i];
    stat[1] = t * (1.0f / DIM_);
  }
  __syncthreads();
  const float inv = 1.0f / sqrtf(stat[1] + 1e-6f);
  y[(size_t)p * DIM_ + c] = d * inv * g[c] + beta[c];
}

// standalone readout for the final (19th) readout
__global__ __launch_bounds__(384) void readout_attn(
    const float* __restrict__ kv, float* __restrict__ lat,
    const float* __restrict__ q_w, const float* __restrict__ out_w,
    const float* __restrict__ out_b, const float* __restrict__ lng,
    const float* __restrict__ lnb)
{
  readout_body(blockIdx.x, kv, lat, q_w, out_w, out_b, lng, lnb);
}

// ---------------------------------------------------------------------------
// head: logits = lat @ head_w + head_b   (32 x 1000)
// ---------------------------------------------------------------------------
__global__ __launch_bounds__(256) void head_kernel(
    const float* __restrict__ lat, const float* __restrict__ hw,
    const float* __restrict__ hb, float* __restrict__ out)
{
  const int b = blockIdx.x;
  for (int n = threadIdx.x; n < NC_; n += 256) {
    float acc = hb[n];
    for (int d = 0; d < DIM_; ++d)
      acc = fmaf(lat[b * DIM_ + d], hw[(size_t)d * NC_ + n], acc);
    out[(size_t)b * NC_ + n] = acc;
  }
}

// ---------------------------------------------------------------------------
extern "C" void kernel_launch(void* const* d_in, const int* in_sizes, int n_in,
                              void* d_out, int out_size, void* d_ws, size_t ws_size,
                              hipStream_t stream)
{
  const float* x       = (const float*)d_in[0];
  const float* stem_w  = (const float*)d_in[1];
  const float* stem_b  = (const float*)d_in[2];
  const float* dw_w    = (const float*)d_in[3];
  const float* dw_b    = (const float*)d_in[4];
  const float* ln_g    = (const float*)d_in[5];
  const float* ln_b    = (const float*)d_in[6];
  const float* w1      = (const float*)d_in[7];
  const float* b1      = (const float*)d_in[8];
  const float* w2      = (const float*)d_in[9];
  const float* b2      = (const float*)d_in[10];
  const float* q_w     = (const float*)d_in[11];
  const float* kv_w    = (const float*)d_in[12];
  const float* out_w   = (const float*)d_in[13];
  const float* out_b   = (const float*)d_in[14];
  const float* latent  = (const float*)d_in[15];
  const float* lln_g   = (const float*)d_in[16];
  const float* lln_b   = (const float*)d_in[17];
  const float* head_w  = (const float*)d_in[18];
  const float* head_b  = (const float*)d_in[19];

  float* ws    = (float*)d_ws;
  float* h     = ws;                         // T_*DIM_
  float* hid   = h + (size_t)T_ * DIM_;      // T_*HID_ — also aliases stem patches
  float* patch = hid;                        // T_*768 fits inside hid
  float* ybuf  = hid + (size_t)T_ * HID_;    // T_*DIM_
  float* kvb   = ybuf + (size_t)T_ * DIM_;   // T_*768
  float* lat   = kvb + (size_t)T_ * 768;     // B_*DIM_
  float* stemT = lat + (size_t)B_ * DIM_;    // 768*384

  const dim3 blk2(16, 16);

  // ---- stem: im2col + GEMM (+bias) ----
  im2col_stem<<<(T_ * KSTEM_ + 255) / 256, 256, 0, stream>>>(x, patch);
  transpose_stem<<<(DIM_ * KSTEM_ + 255) / 256, 256, 0, stream>>>(stem_w, stemT);
  gemmT<64, 64, EPI_BIAS><<<dim3(DIM_ / 64, T_ / 64), blk2, 0, stream>>>(
      patch, stemT, h, stem_b, T_, DIM_, KSTEM_);

  lat_init<<<(B_ * DIM_ + 255) / 256, 256, 0, stream>>>(latent, lat);

  // kv for readout 0
  gemmT<128, 64, EPI_NONE><<<dim3(768 / 64, T_ / 128), blk2, 0, stream>>>(
      h, kv_w, kvb, nullptr, T_, 768, DIM_);

  // ---- blocks: fused [readout(l) || dwconv(l)] -> MLP -> kv(l+1) ----
  for (int l = 0; l < DEPTH_; ++l) {
    dwconv_readout<<<B_ + T_, 384, 0, stream>>>(
        h, dw_w + (size_t)l * DIM_ * 49, dw_b + (size_t)l * DIM_,
        ln_g + (size_t)l * DIM_, ln_b + (size_t)l * DIM_, ybuf,
        kvb, lat, q_w, out_w, out_b, lln_g, lln_b);
    gemmT<128, 128, EPI_BIAS_GELU><<<dim3(HID_ / 128, T_ / 128), blk2, 0, stream>>>(
        ybuf, w1 + (size_t)l * DIM_ * HID_, hid, b1 + (size_t)l * HID_,
        T_, HID_, DIM_);
    gemmT<64, 64, EPI_BIAS_ACC><<<dim3(DIM_ / 64, T_ / 64), blk2, 0, stream>>>(
        hid, w2 + (size_t)l * HID_ * DIM_, h, b2 + (size_t)l * DIM_,
        T_, DIM_, HID_);
    gemmT<128, 64, EPI_NONE><<<dim3(768 / 64, T_ / 128), blk2, 0, stream>>>(
        h, kv_w, kvb, nullptr, T_, 768, DIM_);
  }

  // final readout + head
  readout_attn<<<B_, 384, 0, stream>>>(kvb, lat, q_w, out_w, out_b, lln_g, lln_b);
  head_kernel<<<B_, 256, 0, stream>>>(lat, head_w, head_b, (float*)d_out);
}

// Round 3
// 7058.105 us; speedup vs baseline: 1.5703x; 1.5703x over previous
//
#include <hip/hip_runtime.h>
#include <hip/hip_bf16.h>
#include <math.h>

#define B_    32
#define DIM_  384
#define HID_  1536
#define P_    196     // 14*14 tokens
#define T_    6272    // B_*P_
#define NC_   1000
#define KSTEM_ 768    // 3*16*16
#define DEPTH_ 18
#define SCALE_ 0.05103103630798288f  // 384^-0.5

typedef __attribute__((ext_vector_type(8))) short bf16x8;
typedef __attribute__((ext_vector_type(4))) float f32x4;

enum { EPI_NONE = 0, EPI_BIAS = 1, EPI_BIAS_GELU = 2, EPI_BIAS_ACC = 3 };
enum { MEPI_ATOMIC_BIAS = 0, MEPI_GELU_PAIR = 1, MEPI_ATOMIC = 2 };

__device__ __forceinline__ float gelu_exact(float v) {
  return 0.5f * v * (1.0f + erff(v * 0.70710678118654752f));
}
__device__ __forceinline__ unsigned short f2bf(float x) {
  union { float f; unsigned u; } v; v.f = x;
  unsigned r = v.u + 0x7fffu + ((v.u >> 16) & 1u);
  return (unsigned short)(r >> 16);
}
__device__ __forceinline__ float bf2f(unsigned short h) {
  union { float f; unsigned u; } v; v.u = ((unsigned)h) << 16;
  return v.f;
}

// byte offset of bf16 element (row, k) in a [rows][32] bf16 LDS tile, XOR-swizzled
#define SWZB(row, k) ((((row) * 64) + ((k) * 2)) ^ ((((row) & 7)) << 4))

// ---------------------------------------------------------------------------
// bf16x3 MFMA GEMM: C = A(MxK) @ B^T(NxK) with fp32-grade accuracy.
// A: fp32 [M][K] (split on the fly) or bf16 hi/lo pair [M][K].
// B: always bf16 hi/lo pair [N][K] (pre-transposed weights).
// 128x128 tile, 256 threads = 4 waves (2x2), wave tile 64x64 (4x4 frags),
// K-step 32 (one mfma_f32_16x16x32_bf16 K), split-K via blockIdx.z + atomics.
// ---------------------------------------------------------------------------
template <int BM, int BN, bool APAIR, int EPI>
__global__ __launch_bounds__(256) void gemm_mfma(
    const float* __restrict__ Af,
    const unsigned short* __restrict__ Ah, const unsigned short* __restrict__ Al,
    const unsigned short* __restrict__ Bh, const unsigned short* __restrict__ Bl,
    float* __restrict__ Cf, unsigned short* __restrict__ Chp,
    unsigned short* __restrict__ Clp, const float* __restrict__ bias,
    int M, int N, int K, int KS)
{
  constexpr int WM = BM / 2, WN = BN / 2, TMW = WM / 16, TNW = WN / 16;
  constexpr int TPRA = 256 / BM, KSA = 32 / TPRA;
  constexpr int TPRB = 256 / BN, KSB = 32 / TPRB;

  __shared__ unsigned char smem[(BM + BN) * 128];
  unsigned char* sAh = smem;
  unsigned char* sAl = smem + BM * 64;
  unsigned char* sBh = smem + BM * 128;
  unsigned char* sBl = smem + BM * 128 + BN * 64;

  const int tid = threadIdx.x;
  const int lane = tid & 63;
  const int w = tid >> 6;
  const int wm = w >> 1, wn = w & 1;
  const int r16 = lane & 15, ksl = lane >> 4;

  const int m0 = blockIdx.y * BM, n0 = blockIdx.x * BN;
  const int kbeg = blockIdx.z * KS;

  const int arow = tid / TPRA, ak0 = (tid % TPRA) * KSA;
  const int brow = tid / TPRB, bk0 = (tid % TPRB) * KSB;

  float4 paf[KSA / 4];
  uint4 pah[(KSA + 7) / 8], pal[(KSA + 7) / 8];
  uint4 pbh[(KSB + 7) / 8], pbl[(KSB + 7) / 8];

  const float* agf = Af + (size_t)(m0 + arow) * K + ak0;
  const unsigned short* agh = Ah + (size_t)(m0 + arow) * K + ak0;
  const unsigned short* agl = Al + (size_t)(m0 + arow) * K + ak0;
  const unsigned short* bgh = Bh + (size_t)(n0 + brow) * K + bk0;
  const unsigned short* bgl = Bl + (size_t)(n0 + brow) * K + bk0;

  auto loadA = [&](int kt) {
    if constexpr (APAIR) {
#pragma unroll
      for (int q = 0; q < KSA / 8; ++q) {
        pah[q] = *(const uint4*)(agh + kt + 8 * q);
        pal[q] = *(const uint4*)(agl + kt + 8 * q);
      }
    } else {
#pragma unroll
      for (int q = 0; q < KSA / 4; ++q)
        paf[q] = *(const float4*)(agf + kt + 4 * q);
    }
  };
  auto loadB = [&](int kt) {
#pragma unroll
    for (int q = 0; q < KSB / 8; ++q) {
      pbh[q] = *(const uint4*)(bgh + kt + 8 * q);
      pbl[q] = *(const uint4*)(bgl + kt + 8 * q);
    }
  };
  auto storeA = [&]() {
    if constexpr (APAIR) {
#pragma unroll
      for (int q = 0; q < KSA / 8; ++q) {
        *(uint4*)(sAh + SWZB(arow, ak0 + 8 * q)) = pah[q];
        *(uint4*)(sAl + SWZB(arow, ak0 + 8 * q)) = pal[q];
      }
    } else {
#pragma unroll
      for (int q = 0; q < KSA / 4; ++q) {
        float4 f = paf[q];
        unsigned short h0 = f2bf(f.x), h1 = f2bf(f.y), h2 = f2bf(f.z), h3 = f2bf(f.w);
        unsigned short l0 = f2bf(f.x - bf2f(h0)), l1 = f2bf(f.y - bf2f(h1));
        unsigned short l2 = f2bf(f.z - bf2f(h2)), l3 = f2bf(f.w - bf2f(h3));
        uint2 uh, ul;
        uh.x = (unsigned)h0 | ((unsigned)h1 << 16);
        uh.y = (unsigned)h2 | ((unsigned)h3 << 16);
        ul.x = (unsigned)l0 | ((unsigned)l1 << 16);
        ul.y = (unsigned)l2 | ((unsigned)l3 << 16);
        *(uint2*)(sAh + SWZB(arow, ak0 + 4 * q)) = uh;
        *(uint2*)(sAl + SWZB(arow, ak0 + 4 * q)) = ul;
      }
    }
  };
  auto storeB = [&]() {
#pragma unroll
    for (int q = 0; q < KSB / 8; ++q) {
      *(uint4*)(sBh + SWZB(brow, bk0 + 8 * q)) = pbh[q];
      *(uint4*)(sBl + SWZB(brow, bk0 + 8 * q)) = pbl[q];
    }
  };

  f32x4 acc[TMW][TNW];
#pragma unroll
  for (int i = 0; i < TMW; ++i)
#pragma unroll
    for (int j = 0; j < TNW; ++j) {
      acc[i][j][0] = 0.f; acc[i][j][1] = 0.f; acc[i][j][2] = 0.f; acc[i][j][3] = 0.f;
    }

  loadA(kbeg); loadB(kbeg);
  const int kend = kbeg + KS;
  for (int kt = kbeg; kt < kend; kt += 32) {
    storeA(); storeB();
    __syncthreads();
    if (kt + 32 < kend) { loadA(kt + 32); loadB(kt + 32); }
    bf16x8 a_h[TMW], a_l[TMW], b_h[TNW], b_l[TNW];
#pragma unroll
    for (int i = 0; i < TMW; ++i) {
      const int row = wm * WM + 16 * i + r16;
      a_h[i] = *(const bf16x8*)(sAh + SWZB(row, ksl * 8));
      a_l[i] = *(const bf16x8*)(sAl + SWZB(row, ksl * 8));
    }
#pragma unroll
    for (int j = 0; j < TNW; ++j) {
      const int row = wn * WN + 16 * j + r16;
      b_h[j] = *(const bf16x8*)(sBh + SWZB(row, ksl * 8));
      b_l[j] = *(const bf16x8*)(sBl + SWZB(row, ksl * 8));
    }
#pragma unroll
    for (int i = 0; i < TMW; ++i)
#pragma unroll
      for (int j = 0; j < TNW; ++j) {
        acc[i][j] = __builtin_amdgcn_mfma_f32_16x16x32_bf16(a_h[i], b_h[j], acc[i][j], 0, 0, 0);
        acc[i][j] = __builtin_amdgcn_mfma_f32_16x16x32_bf16(a_h[i], b_l[j], acc[i][j], 0, 0, 0);
        acc[i][j] = __builtin_amdgcn_mfma_f32_16x16x32_bf16(a_l[i], b_h[j], acc[i][j], 0, 0, 0);
      }
    __syncthreads();
  }

#pragma unroll
  for (int i = 0; i < TMW; ++i) {
#pragma unroll
    for (int j = 0; j < TNW; ++j) {
      const int col = n0 + wn * WN + 16 * j + r16;
      float bv = 0.f;
      if constexpr (EPI == MEPI_GELU_PAIR) bv = bias[col];
      else if constexpr (EPI == MEPI_ATOMIC_BIAS) bv = (blockIdx.z == 0) ? bias[col] : 0.f;
#pragma unroll
      for (int r = 0; r < 4; ++r) {
        const int row = m0 + wm * WM + 16 * i + ksl * 4 + r;
        float v = acc[i][j][r];
        if constexpr (EPI == MEPI_GELU_PAIR) {
          v = gelu_exact(v + bv);
          unsigned short hh = f2bf(v);
          Chp[(size_t)row * N + col] = hh;
          Clp[(size_t)row * N + col] = f2bf(v - bf2f(hh));
        } else if constexpr (EPI == MEPI_ATOMIC_BIAS) {
          atomicAdd(&Cf[(size_t)row * N + col], v + bv);
        } else {
          atomicAdd(&Cf[(size_t)row * N + col], v);
        }
      }
    }
  }
}

// ---------------------------------------------------------------------------
// prep kernels
// ---------------------------------------------------------------------------
__global__ void zero_f32(float* __restrict__ p, int n)
{
  const int i = blockIdx.x * 256 + threadIdx.x;
  if (i < n) p[i] = 0.f;
}

// src [L][R][C] fp32 -> dst [L][C][R] bf16 hi/lo (transpose + split)
__global__ void tr_split(const float* __restrict__ src, unsigned short* __restrict__ dh,
                         unsigned short* __restrict__ dl, int L, int R, int C)
{
  const size_t total = (size_t)L * R * C;
  for (size_t idx = (size_t)blockIdx.x * 256 + threadIdx.x; idx < total;
       idx += (size_t)gridDim.x * 256) {
    const size_t lrc = (size_t)R * C;
    const int l = (int)(idx / lrc);
    const size_t rem = idx % lrc;
    const int c = (int)(rem / R), r = (int)(rem % R);
    const float v = src[((size_t)l * R + r) * C + c];
    const unsigned short h = f2bf(v);
    dh[idx] = h;
    dl[idx] = f2bf(v - bf2f(h));
  }
}

// split only (already [N][K])
__global__ void split_only(const float* __restrict__ src, unsigned short* __restrict__ dh,
                           unsigned short* __restrict__ dl, int n)
{
  const int i = blockIdx.x * 256 + threadIdx.x;
  if (i >= n) return;
  const float v = src[i];
  const unsigned short h = f2bf(v);
  dh[i] = h;
  dl[i] = f2bf(v - bf2f(h));
}

// dw_w [18][384][49] -> dwT [18][49][384] fp32
__global__ void tr_dw(const float* __restrict__ src, float* __restrict__ dst)
{
  const int idx = blockIdx.x * 256 + threadIdx.x;
  if (idx >= DEPTH_ * 49 * DIM_) return;
  const int l = idx / (49 * DIM_);
  const int rem = idx % (49 * DIM_);
  const int k = rem / DIM_, c = rem % DIM_;
  dst[idx] = src[((size_t)l * DIM_ + c) * 49 + k];
}

__global__ void im2col_stem(const float* __restrict__ x, float* __restrict__ patch)
{
  const int idx = blockIdx.x * 256 + threadIdx.x;
  if (idx >= T_ * KSTEM_) return;
  const int row = idx / KSTEM_;
  const int k   = idx % KSTEM_;
  const int b   = row / P_;
  const int pix = row % P_;
  const int py = pix / 14, px = pix % 14;
  const int c  = k >> 8;
  const int r  = k & 255;
  const int iy = r >> 4, ix = r & 15;
  patch[idx] = x[((size_t)b * 3 + c) * 50176 + (size_t)(py * 16 + iy) * 224 + (px * 16 + ix)];
}

__global__ void transpose_stem(const float* __restrict__ sw, float* __restrict__ out)
{
  const int idx = blockIdx.x * 256 + threadIdx.x;
  if (idx >= DIM_ * KSTEM_) return;
  const int co = idx / KSTEM_, k = idx % KSTEM_;
  out[(size_t)k * DIM_ + co] = sw[idx];
}

__global__ void lat_init(const float* __restrict__ latent, float* __restrict__ lat)
{
  const int idx = blockIdx.x * 256 + threadIdx.x;
  if (idx < B_ * DIM_) lat[idx] = latent[idx % DIM_];
}

// ---------------------------------------------------------------------------
// Readout body (384 threads)
// ---------------------------------------------------------------------------
__device__ __forceinline__ void readout_body(
    int b, const float* __restrict__ kv, float* __restrict__ lat,
    const float* __restrict__ q_w, const float* __restrict__ out_w,
    const float* __restrict__ out_b, const float* __restrict__ lng,
    const float* __restrict__ lnb)
{
  const int tid = threadIdx.x;
  __shared__ float latS[DIM_], qS[DIM_], oS[DIM_], tS[DIM_];
  __shared__ float aS[P_];
  __shared__ float sS[256];
  __shared__ float redR[6], statR[2];

  latS[tid] = lat[b * DIM_ + tid];
  __syncthreads();

  {
    float acc = 0.f;
    for (int d = 0; d < DIM_; ++d) acc = fmaf(latS[d], q_w[d * DIM_ + tid], acc);
    qS[tid] = acc;
  }
  __syncthreads();

  float my_s = -3.4e38f;
  if (tid < P_) {
    const float* kr = kv + ((size_t)(b * P_ + tid)) * 768;
    float acc = 0.f;
    for (int d = 0; d < DIM_; ++d) acc = fmaf(qS[d], kr[d], acc);
    my_s = acc * SCALE_;
  }
  if (tid < 256) sS[tid] = my_s;
  __syncthreads();
  for (int off = 128; off > 0; off >>= 1) {
    if (tid < off) sS[tid] = fmaxf(sS[tid], sS[tid + off]);
    __syncthreads();
  }
  const float mx = sS[0];
  __syncthreads();
  const float ex = (tid < P_) ? expf(my_s - mx) : 0.f;
  if (tid < 256) sS[tid] = ex;
  __syncthreads();
  for (int off = 128; off > 0; off >>= 1) {
    if (tid < off) sS[tid] += sS[tid + off];
    __syncthreads();
  }
  const float den = sS[0];
  if (tid < P_) aS[tid] = ex / den;
  __syncthreads();

  {
    float acc = 0.f;
    for (int t = 0; t < P_; ++t)
      acc = fmaf(aS[t], kv[((size_t)(b * P_ + t)) * 768 + DIM_ + tid], acc);
    oS[tid] = acc;
  }
  __syncthreads();

  {
    float acc = out_b[tid] + latS[tid];
    for (int d = 0; d < DIM_; ++d) acc = fmaf(oS[d], out_w[d * DIM_ + tid], acc);
    tS[tid] = acc;
  }
  __syncthreads();

  const int lane = tid & 63, wv = tid >> 6;
  const float val = tS[tid];
  float s = val;
#pragma unroll
  for (int off = 32; off > 0; off >>= 1) s += __shfl_down(s, off);
  if (lane == 0) redR[wv] = s;
  __syncthreads();
  if (tid == 0) {
    float t = 0.f;
    for (int i = 0; i < 6; ++i) t += redR[i];
    statR[0] = t * (1.0f / DIM_);
  }
  __syncthreads();
  const float mu = statR[0];
  const float dv = val - mu;
  s = dv * dv;
#pragma unroll
  for (int off = 32; off > 0; off >>= 1) s += __shfl_down(s, off);
  if (lane == 0) redR[wv] = s;
  __syncthreads();
  if (tid == 0) {
    float t = 0.f;
    for (int i = 0; i < 6; ++i) t += redR[i];
    statR[1] = t * (1.0f / DIM_);
  }
  __syncthreads();
  const float inv = 1.0f / sqrtf(statR[1] + 1e-5f);
  lat[b * DIM_ + tid] = dv * inv * lng[tid] + lnb[tid];
}

// ---------------------------------------------------------------------------
// Fused: blocks [0,B_) readout (current kv); [B_, B_+T_) dwconv+LN -> bf16 pair
// ---------------------------------------------------------------------------
__global__ __launch_bounds__(384) void dwconv_readout2(
    const float* __restrict__ h, const float* __restrict__ wT,
    const float* __restrict__ wb, const float* __restrict__ g,
    const float* __restrict__ beta, unsigned short* __restrict__ ybh,
    unsigned short* __restrict__ ybl,
    const float* __restrict__ kv, float* __restrict__ lat,
    const float* __restrict__ q_w, const float* __restrict__ out_w,
    const float* __restrict__ out_b, const float* __restrict__ lng,
    const float* __restrict__ lnb)
{
  if (blockIdx.x < B_) {
    readout_body(blockIdx.x, kv, lat, q_w, out_w, out_b, lng, lnb);
    return;
  }
  const int c = threadIdx.x;
  const int p = blockIdx.x - B_;
  const int b = p / P_, pix = p % P_;
  const int py = pix / 14, px = pix % 14;
  const float* hb = h + (size_t)b * P_ * DIM_;

  float acc = wb[c];
#pragma unroll
  for (int ky = 0; ky < 7; ++ky) {
    const int qy = py + ky - 3;
    if ((unsigned)qy >= 14u) continue;
#pragma unroll
    for (int kx = 0; kx < 7; ++kx) {
      const int qx = px + kx - 3;
      if ((unsigned)qx >= 14u) continue;
      acc = fmaf(hb[(size_t)(qy * 14 + qx) * DIM_ + c], wT[(ky * 7 + kx) * DIM_ + c], acc);
    }
  }

  __shared__ float red[6];
  __shared__ float stat[2];
  const int lane = c & 63, wv = c >> 6;

  float s = acc;
#pragma unroll
  for (int off = 32; off > 0; off >>= 1) s += __shfl_down(s, off);
  if (lane == 0) red[wv] = s;
  __syncthreads();
  if (c == 0) {
    float t = 0.f;
    for (int i = 0; i < 6; ++i) t += red[i];
    stat[0] = t * (1.0f / DIM_);
  }
  __syncthreads();
  const float mu = stat[0];
  const float d = acc - mu;
  s = d * d;
#pragma unroll
  for (int off = 32; off > 0; off >>= 1) s += __shfl_down(s, off);
  if (lane == 0) red[wv] = s;
  __syncthreads();
  if (c == 0) {
    float t = 0.f;
    for (int i = 0; i < 6; ++i) t += red[i];
    stat[1] = t * (1.0f / DIM_);
  }
  __syncthreads();
  const float inv = 1.0f / sqrtf(stat[1] + 1e-6f);
  const float val = d * inv * g[c] + beta[c];
  const unsigned short hh = f2bf(val);
  ybh[(size_t)p * DIM_ + c] = hh;
  ybl[(size_t)p * DIM_ + c] = f2bf(val - bf2f(hh));
}

__global__ __launch_bounds__(384) void readout_attn(
    const float* __restrict__ kv, float* __restrict__ lat,
    const float* __restrict__ q_w, const float* __restrict__ out_w,
    const float* __restrict__ out_b, const float* __restrict__ lng,
    const float* __restrict__ lnb)
{
  readout_body(blockIdx.x, kv, lat, q_w, out_w, out_b, lng, lnb);
}

__global__ __launch_bounds__(256) void head_kernel(
    const float* __restrict__ lat, const float* __restrict__ hw,
    const float* __restrict__ hb, float* __restrict__ out)
{
  const int b = blockIdx.x;
  for (int n = threadIdx.x; n < NC_; n += 256) {
    float acc = hb[n];
    for (int d = 0; d < DIM_; ++d)
      acc = fmaf(lat[b * DIM_ + d], hw[(size_t)d * NC_ + n], acc);
    out[(size_t)b * NC_ + n] = acc;
  }
}

// ---------------------------------------------------------------------------
// fp32 fallback GEMM (previous working path, kept for small ws_size)
// ---------------------------------------------------------------------------
template <int BM, int BN, int EPI>
__global__ __launch_bounds__(256) void gemmT(
    const float* __restrict__ A, const float* __restrict__ Bm,
    float* __restrict__ C, const float* __restrict__ bias,
    int M, int N, int K)
{
  constexpr int TM = BM / 16, TN = BN / 16;
  __shared__ float As[16][BM + 4];
  __shared__ float Bs[16][BN + 4];

  const int tx = threadIdx.x, ty = threadIdx.y;
  const int tid = ty * 16 + tx;
  const int m0 = blockIdx.y * BM, n0 = blockIdx.x * BN;

  const int arow = (BM == 128) ? (tid >> 1) : (tid >> 2);
  const int akq  = (BM == 128) ? ((tid & 1) * 8) : ((tid & 3) * 4);
  const int brow = tid >> 4;
  const int bc0  = (tid & 15) * 4;

  const float* Aptr = A + (size_t)(m0 + arow) * K + akq;
  const float* Bptr = Bm + (size_t)brow * N + n0 + bc0;

  float4 pa[(BM == 128) ? 2 : 1];
  float4 pb[(BN == 128) ? 2 : 1];

  auto loadTile = [&](int kt, float4* ra, float4* rb) {
    ra[0] = *(const float4*)&Aptr[kt];
    if constexpr (BM == 128) ra[1] = *(const float4*)&Aptr[kt + 4];
    rb[0] = *(const float4*)&Bptr[(size_t)kt * N];
    if constexpr (BN == 128) rb[1] = *(const float4*)&Bptr[(size_t)kt * N + 64];
  };
  auto storeTile = [&](const float4* ra, const float4* rb) {
    As[akq + 0][arow] = ra[0].x;
    As[akq + 1][arow] = ra[0].y;
    As[akq + 2][arow] = ra[0].z;
    As[akq + 3][arow] = ra[0].w;
    if constexpr (BM == 128) {
      As[akq + 4][arow] = ra[1].x;
      As[akq + 5][arow] = ra[1].y;
      As[akq + 6][arow] = ra[1].z;
      As[akq + 7][arow] = ra[1].w;
    }
    *(float4*)&Bs[brow][bc0] = rb[0];
    if constexpr (BN == 128) *(float4*)&Bs[brow][bc0 + 64] = rb[1];
  };

  float acc[TM][TN] = {};

  loadTile(0, pa, pb);
  for (int kt = 0; kt < K; kt += 16) {
    storeTile(pa, pb);
    __syncthreads();
    if ((kt + 16) < K) loadTile(kt + 16, pa, pb);
#pragma unroll
    for (int kk = 0; kk < 16; ++kk) {
      float a[TM], b[TN];
#pragma unroll
      for (int i = 0; i < TM; i += 4)
        *(float4*)&a[i] = *(const float4*)&As[kk][ty * TM + i];
#pragma unroll
      for (int j = 0; j < TN; j += 4)
        *(float4*)&b[j] = *(const float4*)&Bs[kk][tx * TN + j];
#pragma unroll
      for (int i = 0; i < TM; ++i)
#pragma unroll
        for (int j = 0; j < TN; ++j)
          acc[i][j] = fmaf(a[i], b[j], acc[i][j]);
    }
    __syncthreads();
  }

  float bsv[TN];
  if (EPI != EPI_NONE) {
#pragma unroll
    for (int j = 0; j < TN; j += 4)
      *(float4*)&bsv[j] = *(const float4*)&bias[n0 + tx * TN + j];
  }
#pragma unroll
  for (int i = 0; i < TM; ++i) {
    float* crow = &C[(size_t)(m0 + ty * TM + i) * N + n0 + tx * TN];
#pragma unroll
    for (int j = 0; j < TN; j += 4) {
      float4 v;
      v.x = acc[i][j]; v.y = acc[i][j + 1]; v.z = acc[i][j + 2]; v.w = acc[i][j + 3];
      if (EPI == EPI_BIAS) {
        v.x += bsv[j]; v.y += bsv[j + 1]; v.z += bsv[j + 2]; v.w += bsv[j + 3];
      } else if (EPI == EPI_BIAS_GELU) {
        v.x = gelu_exact(v.x + bsv[j]);
        v.y = gelu_exact(v.y + bsv[j + 1]);
        v.z = gelu_exact(v.z + bsv[j + 2]);
        v.w = gelu_exact(v.w + bsv[j + 3]);
      } else if (EPI == EPI_BIAS_ACC) {
        float4 c = *(const float4*)&crow[j];
        v.x += c.x + bsv[j]; v.y += c.y + bsv[j + 1];
        v.z += c.z + bsv[j + 2]; v.w += c.w + bsv[j + 3];
      }
      *(float4*)&crow[j] = v;
    }
  }
}

__global__ __launch_bounds__(384) void dwconv_readout_old(
    const float* __restrict__ h, const float* __restrict__ w,
    const float* __restrict__ wb, const float* __restrict__ g,
    const float* __restrict__ beta, float* __restrict__ y,
    const float* __restrict__ kv, float* __restrict__ lat,
    const float* __restrict__ q_w, const float* __restrict__ out_w,
    const float* __restrict__ out_b, const float* __restrict__ lng,
    const float* __restrict__ lnb)
{
  if (blockIdx.x < B_) {
    readout_body(blockIdx.x, kv, lat, q_w, out_w, out_b, lng, lnb);
    return;
  }
  const int c = threadIdx.x;
  const int p = blockIdx.x - B_;
  const int b = p / P_, pix = p % P_;
  const int py = pix / 14, px = pix % 14;
  const float* hb = h + (size_t)b * P_ * DIM_;

  float acc = wb[c];
  const float* wr = w + c * 49;
#pragma unroll
  for (int ky = 0; ky < 7; ++ky) {
    const int qy = py + ky - 3;
    if ((unsigned)qy >= 14u) continue;
#pragma unroll
    for (int kx = 0; kx < 7; ++kx) {
      const int qx = px + kx - 3;
      if ((unsigned)qx >= 14u) continue;
      acc = fmaf(hb[(size_t)(qy * 14 + qx) * DIM_ + c], wr[ky * 7 + kx], acc);
    }
  }

  __shared__ float red[6];
  __shared__ float stat[2];
  const int lane = c & 63, wv = c >> 6;
  float s = acc;
#pragma unroll
  for (int off = 32; off > 0; off >>= 1) s += __shfl_down(s, off);
  if (lane == 0) red[wv] = s;
  __syncthreads();
  if (c == 0) {
    float t = 0.f;
    for (int i = 0; i < 6; ++i) t += red[i];
    stat[0] = t * (1.0f / DIM_);
  }
  __syncthreads();
  const float mu = stat[0];
  const float d = acc - mu;
  s = d * d;
#pragma unroll
  for (int off = 32; off > 0; off >>= 1) s += __shfl_down(s, off);
  if (lane == 0) red[wv] = s;
  __syncthreads();
  if (c == 0) {
    float t = 0.f;
    for (int i = 0; i < 6; ++i) t += red[i];
    stat[1] = t * (1.0f / DIM_);
  }
  __syncthreads();
  const float inv = 1.0f / sqrtf(stat[1] + 1e-6f);
  y[(size_t)p * DIM_ + c] = d * inv * g[c] + beta[c];
}

// ---------------------------------------------------------------------------
extern "C" void kernel_launch(void* const* d_in, const int* in_sizes, int n_in,
                              void* d_out, int out_size, void* d_ws, size_t ws_size,
                              hipStream_t stream)
{
  const float* x       = (const float*)d_in[0];
  const float* stem_w  = (const float*)d_in[1];
  const float* stem_b  = (const float*)d_in[2];
  const float* dw_w    = (const float*)d_in[3];
  const float* dw_b    = (const float*)d_in[4];
  const float* ln_g    = (const float*)d_in[5];
  const float* ln_b    = (const float*)d_in[6];
  const float* w1      = (const float*)d_in[7];
  const float* b1      = (const float*)d_in[8];
  const float* w2      = (const float*)d_in[9];
  const float* b2      = (const float*)d_in[10];
  const float* q_w     = (const float*)d_in[11];
  const float* kv_w    = (const float*)d_in[12];
  const float* out_w   = (const float*)d_in[13];
  const float* out_b   = (const float*)d_in[14];
  const float* latent  = (const float*)d_in[15];
  const float* lln_g   = (const float*)d_in[16];
  const float* lln_b   = (const float*)d_in[17];
  const float* head_w  = (const float*)d_in[18];
  const float* head_b  = (const float*)d_in[19];

  // exact byte need of the MFMA path (all chunks are 256B-aligned already)
  const size_t NEED_NEW =
      (size_t)T_ * DIM_ * 4 + (size_t)T_ * 768 * 4 +
      2 * (size_t)T_ * DIM_ * 2 + 2 * (size_t)T_ * HID_ * 2 +
      4 * (size_t)DEPTH_ * HID_ * DIM_ * 2 +
      2 * (size_t)768 * DIM_ * 2 + 2 * (size_t)DIM_ * KSTEM_ * 2 +
      (size_t)DEPTH_ * 49 * DIM_ * 4 + (size_t)B_ * DIM_ * 4;

  if (ws_size >= NEED_NEW) {
    char* base = (char*)d_ws;
    size_t off = 0;
    auto alloc = [&](size_t bytes) {
      void* p = base + off;
      off += (bytes + 255) & ~(size_t)255;
      return p;
    };
    float* h      = (float*)alloc((size_t)T_ * DIM_ * 4);
    float* kvb    = (float*)alloc((size_t)T_ * 768 * 4);
    unsigned short* ybh  = (unsigned short*)alloc((size_t)T_ * DIM_ * 2);
    unsigned short* ybl  = (unsigned short*)alloc((size_t)T_ * DIM_ * 2);
    unsigned short* hidh = (unsigned short*)alloc((size_t)T_ * HID_ * 2);
    unsigned short* hidl = (unsigned short*)alloc((size_t)T_ * HID_ * 2);
    unsigned short* w1h  = (unsigned short*)alloc((size_t)DEPTH_ * HID_ * DIM_ * 2);
    unsigned short* w1l  = (unsigned short*)alloc((size_t)DEPTH_ * HID_ * DIM_ * 2);
    unsigned short* w2h  = (unsigned short*)alloc((size_t)DEPTH_ * DIM_ * HID_ * 2);
    unsigned short* w2l  = (unsigned short*)alloc((size_t)DEPTH_ * DIM_ * HID_ * 2);
    unsigned short* kvh  = (unsigned short*)alloc((size_t)768 * DIM_ * 2);
    unsigned short* kvl  = (unsigned short*)alloc((size_t)768 * DIM_ * 2);
    unsigned short* sth  = (unsigned short*)alloc((size_t)DIM_ * KSTEM_ * 2);
    unsigned short* stl  = (unsigned short*)alloc((size_t)DIM_ * KSTEM_ * 2);
    float* dwT   = (float*)alloc((size_t)DEPTH_ * 49 * DIM_ * 4);
    float* lat   = (float*)alloc((size_t)B_ * DIM_ * 4);
    float* patch = (float*)hidh;   // T_*768*4 == T_*HID_*2 bytes; used only in prolog

    // ---- prep (all independent) ----
    im2col_stem<<<(T_ * KSTEM_ + 255) / 256, 256, 0, stream>>>(x, patch);
    split_only<<<(DIM_ * KSTEM_ + 255) / 256, 256, 0, stream>>>(stem_w, sth, stl, DIM_ * KSTEM_);
    tr_split<<<4096, 256, 0, stream>>>(w1, w1h, w1l, DEPTH_, DIM_, HID_);
    tr_split<<<4096, 256, 0, stream>>>(w2, w2h, w2l, DEPTH_, HID_, DIM_);
    tr_split<<<1024, 256, 0, stream>>>(kv_w, kvh, kvl, 1, DIM_, 768);
    tr_dw<<<(DEPTH_ * 49 * DIM_ + 255) / 256, 256, 0, stream>>>(dw_w, dwT);
    lat_init<<<(B_ * DIM_ + 255) / 256, 256, 0, stream>>>(latent, lat);

    // ---- stem: h = patch @ stemW^T + stem_b  (split-K=2, atomic) ----
    zero_f32<<<(T_ * DIM_ + 255) / 256, 256, 0, stream>>>(h, T_ * DIM_);
    gemm_mfma<128, 128, false, MEPI_ATOMIC_BIAS>
        <<<dim3(DIM_ / 128, T_ / 128, 2), 256, 0, stream>>>(
        patch, nullptr, nullptr, sth, stl, h, nullptr, nullptr, stem_b,
        T_, DIM_, KSTEM_, 384);

    // ---- kv for readout 0 ----
    zero_f32<<<(T_ * 768 + 255) / 256, 256, 0, stream>>>(kvb, T_ * 768);
    gemm_mfma<128, 128, false, MEPI_ATOMIC>
        <<<dim3(768 / 128, T_ / 128, 2), 256, 0, stream>>>(
        h, nullptr, nullptr, kvh, kvl, kvb, nullptr, nullptr, nullptr,
        T_, 768, DIM_, 192);

    // ---- blocks ----
    for (int l = 0; l < DEPTH_; ++l) {
      dwconv_readout2<<<B_ + T_, 384, 0, stream>>>(
          h, dwT + (size_t)l * 49 * DIM_, dw_b + (size_t)l * DIM_,
          ln_g + (size_t)l * DIM_, ln_b + (size_t)l * DIM_, ybh, ybl,
          kvb, lat, q_w, out_w, out_b, lln_g, lln_b);
      gemm_mfma<128, 128, true, MEPI_GELU_PAIR>
          <<<dim3(HID_ / 128, T_ / 128, 1), 256, 0, stream>>>(
          nullptr, ybh, ybl, w1h + (size_t)l * HID_ * DIM_, w1l + (size_t)l * HID_ * DIM_,
          nullptr, hidh, hidl, b1 + (size_t)l * HID_, T_, HID_, DIM_, 384);
      gemm_mfma<128, 128, true, MEPI_ATOMIC_BIAS>
          <<<dim3(DIM_ / 128, T_ / 128, 4), 256, 0, stream>>>(
          nullptr, hidh, hidl, w2h + (size_t)l * DIM_ * HID_, w2l + (size_t)l * DIM_ * HID_,
          h, nullptr, nullptr, b2 + (size_t)l * DIM_, T_, DIM_, HID_, 384);
      zero_f32<<<(T_ * 768 + 255) / 256, 256, 0, stream>>>(kvb, T_ * 768);
      gemm_mfma<128, 128, false, MEPI_ATOMIC>
          <<<dim3(768 / 128, T_ / 128, 2), 256, 0, stream>>>(
          h, nullptr, nullptr, kvh, kvl, kvb, nullptr, nullptr, nullptr,
          T_, 768, DIM_, 192);
    }

    readout_attn<<<B_, 384, 0, stream>>>(kvb, lat, q_w, out_w, out_b, lln_g, lln_b);
    head_kernel<<<B_, 256, 0, stream>>>(lat, head_w, head_b, (float*)d_out);
    return;
  }

  // =================== fp32 fallback (previous working path) ===================
  float* ws    = (float*)d_ws;
  float* h     = ws;
  float* hid   = h + (size_t)T_ * DIM_;
  float* patch = hid;
  float* ybuf  = hid + (size_t)T_ * HID_;
  float* kvb   = ybuf + (size_t)T_ * DIM_;
  float* lat   = kvb + (size_t)T_ * 768;
  float* stemT = lat + (size_t)B_ * DIM_;

  const dim3 blk2(16, 16);

  im2col_stem<<<(T_ * KSTEM_ + 255) / 256, 256, 0, stream>>>(x, patch);
  transpose_stem<<<(DIM_ * KSTEM_ + 255) / 256, 256, 0, stream>>>(stem_w, stemT);
  gemmT<64, 64, EPI_BIAS><<<dim3(DIM_ / 64, T_ / 64), blk2, 0, stream>>>(
      patch, stemT, h, stem_b, T_, DIM_, KSTEM_);
  lat_init<<<(B_ * DIM_ + 255) / 256, 256, 0, stream>>>(latent, lat);
  gemmT<128, 64, EPI_NONE><<<dim3(768 / 64, T_ / 128), blk2, 0, stream>>>(
      h, kv_w, kvb, nullptr, T_, 768, DIM_);
  for (int l = 0; l < DEPTH_; ++l) {
    dwconv_readout_old<<<B_ + T_, 384, 0, stream>>>(
        h, dw_w + (size_t)l * DIM_ * 49, dw_b + (size_t)l * DIM_,
        ln_g + (size_t)l * DIM_, ln_b + (size_t)l * DIM_, ybuf,
        kvb, lat, q_w, out_w, out_b, lln_g, lln_b);
    gemmT<128, 128, EPI_BIAS_GELU><<<dim3(HID_ / 128, T_ / 128), blk2, 0, stream>>>(
        ybuf, w1 + (size_t)l * DIM_ * HID_, hid, b1 + (size_t)l * HID_,
        T_, HID_, DIM_);
    gemmT<64, 64, EPI_BIAS_ACC><<<dim3(DIM_ / 64, T_ / 64), blk2, 0, stream>>>(
        hid, w2 + (size_t)l * HID_ * DIM_, h, b2 + (size_t)l * DIM_,
        T_, DIM_, HID_);
    gemmT<128, 64, EPI_NONE><<<dim3(768 / 64, T_ / 128), blk2, 0, stream>>>(
        h, kv_w, kvb, nullptr, T_, 768, DIM_);
  }
  readout_attn<<<B_, 384, 0, stream>>>(kvb, lat, q_w, out_w, out_b, lln_g, lln_b);
  head_kernel<<<B_, 256, 0, stream>>>(lat, head_w, head_b, (float*)d_out);
}

// Round 5
// 4959.217 us; speedup vs baseline: 2.2348x; 1.4232x over previous
//
#include <hip/hip_runtime.h>
#include <hip/hip_bf16.h>
#include <math.h>

#define B_    32
#define DIM_  384
#define HID_  1536
#define P_    196     // 14*14 tokens
#define T_    6272    // B_*P_
#define NC_   1000
#define KSTEM_ 768    // 3*16*16
#define DEPTH_ 18
#define SCALE_ 0.05103103630798288f  // 384^-0.5

typedef __attribute__((ext_vector_type(8))) short bf16x8;
typedef __attribute__((ext_vector_type(4))) float f32x4;

enum { GEPI_NONE = 0, GEPI_BIAS = 1, GEPI_GELU = 2, GEPI_RESID = 3 };

__device__ __forceinline__ float gelu_exact(float v) {
  return 0.5f * v * (1.0f + erff(v * 0.70710678118654752f));
}
__device__ __forceinline__ unsigned short f2bf(float x) {
  union { float f; unsigned u; } v; v.f = x;
  unsigned r = v.u + 0x7fffu + ((v.u >> 16) & 1u);
  return (unsigned short)(r >> 16);
}
__device__ __forceinline__ float bf2f(unsigned short h) {
  union { float f; unsigned u; } v; v.u = ((unsigned)h) << 16;
  return v.f;
}

// byte offset of bf16 element (row, k) in a [rows][32] bf16 LDS plane, XOR-swizzled
#define SWZB(row, k) ((((row) * 64) + ((k) * 2)) ^ ((((row) & 7)) << 4))

// ---------------------------------------------------------------------------
// bf16x3 MFMA GEMM: C = A(MxK, f32) @ B^T(NxK, bf16 hi/lo planes) [+epilogue]
// A is split hi/lo on the fly during LDS staging (byte-identical numerics to
// storing pairs; VALU is idle so the split is free).
// 256 threads = 4 waves (2x2), wave tile (BM/2)x(BN/2), K-step 32.
// No split-K, no atomics: every output written exactly once.
// ---------------------------------------------------------------------------
template <int BM, int BN, int EPI>
__global__ __launch_bounds__(256) void gemm2(
    const float* __restrict__ A,
    const unsigned short* __restrict__ Bh, const unsigned short* __restrict__ Bl,
    float* __restrict__ C, const float* __restrict__ bias,
    int M, int N, int K)
{
  constexpr int WM = BM / 2, WN = BN / 2, TMW = WM / 16, TNW = WN / 16;
  constexpr int TPRA = 256 / BM, EA = 32 / TPRA;   // f32 elems per thread (A)
  constexpr int TPRB = 256 / BN, EB = 32 / TPRB;   // bf16 elems per thread per plane (B)

  __shared__ unsigned char smem[(BM + BN) * 128];
  unsigned char* sAh = smem;
  unsigned char* sAl = smem + BM * 64;
  unsigned char* sBh = smem + BM * 128;
  unsigned char* sBl = smem + BM * 128 + BN * 64;

  const int tid = threadIdx.x;
  const int lane = tid & 63;
  const int w = tid >> 6;
  const int wm = w >> 1, wn = w & 1;
  const int r16 = lane & 15, ksl = lane >> 4;

  const int m0 = blockIdx.y * BM, n0 = blockIdx.x * BN;

  const int arow = tid / TPRA, ak0 = (tid % TPRA) * EA;
  const int brow = tid / TPRB, bk0 = (tid % TPRB) * EB;

  const float* ag = A + (size_t)(m0 + arow) * K + ak0;
  const unsigned short* bgh = Bh + (size_t)(n0 + brow) * K + bk0;
  const unsigned short* bgl = Bl + (size_t)(n0 + brow) * K + bk0;

  float4 pa[EA / 4];
  uint4 pbh[EB / 8], pbl[EB / 8];

  auto loadA = [&](int kt) {
#pragma unroll
    for (int q = 0; q < EA / 4; ++q) pa[q] = *(const float4*)(ag + kt + 4 * q);
  };
  auto loadB = [&](int kt) {
#pragma unroll
    for (int q = 0; q < EB / 8; ++q) {
      pbh[q] = *(const uint4*)(bgh + kt + 8 * q);
      pbl[q] = *(const uint4*)(bgl + kt + 8 * q);
    }
  };
  auto storeA = [&]() {
#pragma unroll
    for (int q = 0; q < EA / 4; ++q) {
      const float4 f = pa[q];
      const unsigned short h0 = f2bf(f.x), h1 = f2bf(f.y), h2 = f2bf(f.z), h3 = f2bf(f.w);
      const unsigned short l0 = f2bf(f.x - bf2f(h0)), l1 = f2bf(f.y - bf2f(h1));
      const unsigned short l2 = f2bf(f.z - bf2f(h2)), l3 = f2bf(f.w - bf2f(h3));
      uint2 uh, ul;
      uh.x = (unsigned)h0 | ((unsigned)h1 << 16);
      uh.y = (unsigned)h2 | ((unsigned)h3 << 16);
      ul.x = (unsigned)l0 | ((unsigned)l1 << 16);
      ul.y = (unsigned)l2 | ((unsigned)l3 << 16);
      *(uint2*)(sAh + SWZB(arow, ak0 + 4 * q)) = uh;
      *(uint2*)(sAl + SWZB(arow, ak0 + 4 * q)) = ul;
    }
  };
  auto storeB = [&]() {
#pragma unroll
    for (int q = 0; q < EB / 8; ++q) {
      *(uint4*)(sBh + SWZB(brow, bk0 + 8 * q)) = pbh[q];
      *(uint4*)(sBl + SWZB(brow, bk0 + 8 * q)) = pbl[q];
    }
  };

  f32x4 acc[TMW][TNW];
#pragma unroll
  for (int i = 0; i < TMW; ++i)
#pragma unroll
    for (int j = 0; j < TNW; ++j) {
      acc[i][j][0] = 0.f; acc[i][j][1] = 0.f; acc[i][j][2] = 0.f; acc[i][j][3] = 0.f;
    }

  loadA(0); loadB(0);
  for (int kt = 0; kt < K; kt += 32) {
    storeA(); storeB();
    __syncthreads();
    if (kt + 32 < K) { loadA(kt + 32); loadB(kt + 32); }
    bf16x8 a_h[TMW], a_l[TMW], b_h[TNW], b_l[TNW];
#pragma unroll
    for (int i = 0; i < TMW; ++i) {
      const int row = wm * WM + 16 * i + r16;
      a_h[i] = *(const bf16x8*)(sAh + SWZB(row, ksl * 8));
      a_l[i] = *(const bf16x8*)(sAl + SWZB(row, ksl * 8));
    }
#pragma unroll
    for (int j = 0; j < TNW; ++j) {
      const int row = wn * WN + 16 * j + r16;
      b_h[j] = *(const bf16x8*)(sBh + SWZB(row, ksl * 8));
      b_l[j] = *(const bf16x8*)(sBl + SWZB(row, ksl * 8));
    }
#pragma unroll
    for (int i = 0; i < TMW; ++i)
#pragma unroll
      for (int j = 0; j < TNW; ++j) {
        acc[i][j] = __builtin_amdgcn_mfma_f32_16x16x32_bf16(a_h[i], b_h[j], acc[i][j], 0, 0, 0);
        acc[i][j] = __builtin_amdgcn_mfma_f32_16x16x32_bf16(a_h[i], b_l[j], acc[i][j], 0, 0, 0);
        acc[i][j] = __builtin_amdgcn_mfma_f32_16x16x32_bf16(a_l[i], b_h[j], acc[i][j], 0, 0, 0);
      }
    __syncthreads();
  }

  // epilogue: 16 consecutive cols per 16-lane group -> 64B full-line stores
#pragma unroll
  for (int i = 0; i < TMW; ++i) {
#pragma unroll
    for (int j = 0; j < TNW; ++j) {
      const int col = n0 + wn * WN + 16 * j + r16;
      float bv = 0.f;
      if constexpr (EPI == GEPI_BIAS || EPI == GEPI_GELU || EPI == GEPI_RESID)
        bv = bias[col];
#pragma unroll
      for (int r = 0; r < 4; ++r) {
        const int row = m0 + wm * WM + 16 * i + ksl * 4 + r;
        float v = acc[i][j][r];
        float* cp = &C[(size_t)row * N + col];
        if constexpr (EPI == GEPI_GELU) {
          *cp = gelu_exact(v + bv);
        } else if constexpr (EPI == GEPI_RESID) {
          *cp = *cp + v + bv;
        } else if constexpr (EPI == GEPI_BIAS) {
          *cp = v + bv;
        } else {
          *cp = v;
        }
      }
    }
  }
}

// ---------------------------------------------------------------------------
// prep kernels
// ---------------------------------------------------------------------------
// [L][R][C] f32 -> [L][C][R] bf16 hi/lo planes via 32x32 LDS tile.
// Coalesced reads (along C) and coalesced writes (along R). R,C % 32 == 0.
// grid = (C/32, R/32, L), block = 256.
__global__ __launch_bounds__(256) void tr_split_tiled(
    const float* __restrict__ src, unsigned short* __restrict__ dh,
    unsigned short* __restrict__ dl, int R, int C)
{
  __shared__ float tile[32][33];
  const int l  = blockIdx.z;
  const int c0 = blockIdx.x * 32, r0 = blockIdx.y * 32;
  const int tx = threadIdx.x & 31, ty = threadIdx.x >> 5;   // ty 0..7

#pragma unroll
  for (int i = 0; i < 4; ++i) {
    const int rl = ty + 8 * i;
    tile[rl][tx] = src[((size_t)l * R + r0 + rl) * C + c0 + tx];
  }
  __syncthreads();
#pragma unroll
  for (int i = 0; i < 4; ++i) {
    const int cl = ty + 8 * i;
    const float v = tile[tx][cl];          // (r0+tx, c0+cl)
    const unsigned short h = f2bf(v);
    const size_t oidx = ((size_t)l * C + c0 + cl) * R + r0 + tx;
    dh[oidx] = h;
    dl[oidx] = f2bf(v - bf2f(h));
  }
}

// split only (already [N][K])
__global__ void split_only(const float* __restrict__ src, unsigned short* __restrict__ dh,
                           unsigned short* __restrict__ dl, int n)
{
  const int i = blockIdx.x * 256 + threadIdx.x;
  if (i >= n) return;
  const float v = src[i];
  const unsigned short h = f2bf(v);
  dh[i] = h;
  dl[i] = f2bf(v - bf2f(h));
}

// dw_w [18][384][49] -> dwT [18][49][384] fp32
__global__ void tr_dw(const float* __restrict__ src, float* __restrict__ dst)
{
  const int idx = blockIdx.x * 256 + threadIdx.x;
  if (idx >= DEPTH_ * 49 * DIM_) return;
  const int l = idx / (49 * DIM_);
  const int rem = idx % (49 * DIM_);
  const int k = rem / DIM_, c = rem % DIM_;
  dst[idx] = src[((size_t)l * DIM_ + c) * 49 + k];
}

__global__ void im2col_stem(const float* __restrict__ x, float* __restrict__ patch)
{
  const int idx = blockIdx.x * 256 + threadIdx.x;
  if (idx >= T_ * KSTEM_) return;
  const int row = idx / KSTEM_;
  const int k   = idx % KSTEM_;
  const int b   = row / P_;
  const int pix = row % P_;
  const int py = pix / 14, px = pix % 14;
  const int c  = k >> 8;
  const int r  = k & 255;
  const int iy = r >> 4, ix = r & 15;
  patch[idx] = x[((size_t)b * 3 + c) * 50176 + (size_t)(py * 16 + iy) * 224 + (px * 16 + ix)];
}

__global__ void lat_init(const float* __restrict__ latent, float* __restrict__ lat)
{
  const int idx = blockIdx.x * 256 + threadIdx.x;
  if (idx < B_ * DIM_) lat[idx] = latent[idx % DIM_];
}

// ---------------------------------------------------------------------------
// Readout body (384 threads)
// ---------------------------------------------------------------------------
__device__ __forceinline__ void readout_body(
    int b, const float* __restrict__ kv, float* __restrict__ lat,
    const float* __restrict__ q_w, const float* __restrict__ out_w,
    const float* __restrict__ out_b, const float* __restrict__ lng,
    const float* __restrict__ lnb)
{
  const int tid = threadIdx.x;
  __shared__ float latS[DIM_], qS[DIM_], oS[DIM_], tS[DIM_];
  __shared__ float aS[P_];
  __shared__ float sS[256];
  __shared__ float redR[6], statR[2];

  latS[tid] = lat[b * DIM_ + tid];
  __syncthreads();

  {
    float acc = 0.f;
    for (int d = 0; d < DIM_; ++d) acc = fmaf(latS[d], q_w[d * DIM_ + tid], acc);
    qS[tid] = acc;
  }
  __syncthreads();

  float my_s = -3.4e38f;
  if (tid < P_) {
    const float* kr = kv + ((size_t)(b * P_ + tid)) * 768;
    float acc = 0.f;
    for (int d = 0; d < DIM_; ++d) acc = fmaf(qS[d], kr[d], acc);
    my_s = acc * SCALE_;
  }
  if (tid < 256) sS[tid] = my_s;
  __syncthreads();
  for (int off = 128; off > 0; off >>= 1) {
    if (tid < off) sS[tid] = fmaxf(sS[tid], sS[tid + off]);
    __syncthreads();
  }
  const float mx = sS[0];
  __syncthreads();
  const float ex = (tid < P_) ? expf(my_s - mx) : 0.f;
  if (tid < 256) sS[tid] = ex;
  __syncthreads();
  for (int off = 128; off > 0; off >>= 1) {
    if (tid < off) sS[tid] += sS[tid + off];
    __syncthreads();
  }
  const float den = sS[0];
  if (tid < P_) aS[tid] = ex / den;
  __syncthreads();

  {
    float acc = 0.f;
    for (int t = 0; t < P_; ++t)
      acc = fmaf(aS[t], kv[((size_t)(b * P_ + t)) * 768 + DIM_ + tid], acc);
    oS[tid] = acc;
  }
  __syncthreads();

  {
    float acc = out_b[tid] + latS[tid];
    for (int d = 0; d < DIM_; ++d) acc = fmaf(oS[d], out_w[d * DIM_ + tid], acc);
    tS[tid] = acc;
  }
  __syncthreads();

  const int lane = tid & 63, wv = tid >> 6;
  const float val = tS[tid];
  float s = val;
#pragma unroll
  for (int off = 32; off > 0; off >>= 1) s += __shfl_down(s, off);
  if (lane == 0) redR[wv] = s;
  __syncthreads();
  if (tid == 0) {
    float t = 0.f;
    for (int i = 0; i < 6; ++i) t += redR[i];
    statR[0] = t * (1.0f / DIM_);
  }
  __syncthreads();
  const float mu = statR[0];
  const float dv = val - mu;
  s = dv * dv;
#pragma unroll
  for (int off = 32; off > 0; off >>= 1) s += __shfl_down(s, off);
  if (lane == 0) redR[wv] = s;
  __syncthreads();
  if (tid == 0) {
    float t = 0.f;
    for (int i = 0; i < 6; ++i) t += redR[i];
    statR[1] = t * (1.0f / DIM_);
  }
  __syncthreads();
  const float inv = 1.0f / sqrtf(statR[1] + 1e-5f);
  lat[b * DIM_ + tid] = dv * inv * lng[tid] + lnb[tid];
}

// ---------------------------------------------------------------------------
// Fused: blocks [0,B_) readout (current kv); [B_, B_+T_) dwconv+LN -> f32 yb
// ---------------------------------------------------------------------------
__global__ __launch_bounds__(384) void dwconv_readout(
    const float* __restrict__ h, const float* __restrict__ wT,
    const float* __restrict__ wb, const float* __restrict__ g,
    const float* __restrict__ beta, float* __restrict__ y,
    const float* __restrict__ kv, float* __restrict__ lat,
    const float* __restrict__ q_w, const float* __restrict__ out_w,
    const float* __restrict__ out_b, const float* __restrict__ lng,
    const float* __restrict__ lnb)
{
  if (blockIdx.x < B_) {
    readout_body(blockIdx.x, kv, lat, q_w, out_w, out_b, lng, lnb);
    return;
  }
  const int c = threadIdx.x;
  const int p = blockIdx.x - B_;
  const int b = p / P_, pix = p % P_;
  const int py = pix / 14, px = pix % 14;
  const float* hb = h + (size_t)b * P_ * DIM_;

  float acc = wb[c];
#pragma unroll
  for (int ky = 0; ky < 7; ++ky) {
    const int qy = py + ky - 3;
    if ((unsigned)qy >= 14u) continue;
#pragma unroll
    for (int kx = 0; kx < 7; ++kx) {
      const int qx = px + kx - 3;
      if ((unsigned)qx >= 14u) continue;
      acc = fmaf(hb[(size_t)(qy * 14 + qx) * DIM_ + c], wT[(ky * 7 + kx) * DIM_ + c], acc);
    }
  }

  __shared__ float red[6];
  __shared__ float stat[2];
  const int lane = c & 63, wv = c >> 6;

  float s = acc;
#pragma unroll
  for (int off = 32; off > 0; off >>= 1) s += __shfl_down(s, off);
  if (lane == 0) red[wv] = s;
  __syncthreads();
  if (c == 0) {
    float t = 0.f;
    for (int i = 0; i < 6; ++i) t += red[i];
    stat[0] = t * (1.0f / DIM_);
  }
  __syncthreads();
  const float mu = stat[0];
  const float d = acc - mu;
  s = d * d;
#pragma unroll
  for (int off = 32; off > 0; off >>= 1) s += __shfl_down(s, off);
  if (lane == 0) red[wv] = s;
  __syncthreads();
  if (c == 0) {
    float t = 0.f;
    for (int i = 0; i < 6; ++i) t += red[i];
    stat[1] = t * (1.0f / DIM_);
  }
  __syncthreads();
  const float inv = 1.0f / sqrtf(stat[1] + 1e-6f);
  y[(size_t)p * DIM_ + c] = d * inv * g[c] + beta[c];
}

__global__ __launch_bounds__(384) void readout_attn(
    const float* __restrict__ kv, float* __restrict__ lat,
    const float* __restrict__ q_w, const float* __restrict__ out_w,
    const float* __restrict__ out_b, const float* __restrict__ lng,
    const float* __restrict__ lnb)
{
  readout_body(blockIdx.x, kv, lat, q_w, out_w, out_b, lng, lnb);
}

__global__ __launch_bounds__(256) void head_kernel(
    const float* __restrict__ lat, const float* __restrict__ hw,
    const float* __restrict__ hb, float* __restrict__ out)
{
  const int b = blockIdx.x;
  for (int n = threadIdx.x; n < NC_; n += 256) {
    float acc = hb[n];
    for (int d = 0; d < DIM_; ++d)
      acc = fmaf(lat[b * DIM_ + d], hw[(size_t)d * NC_ + n], acc);
    out[(size_t)b * NC_ + n] = acc;
  }
}

// ---------------------------------------------------------------------------
extern "C" void kernel_launch(void* const* d_in, const int* in_sizes, int n_in,
                              void* d_out, int out_size, void* d_ws, size_t ws_size,
                              hipStream_t stream)
{
  const float* x       = (const float*)d_in[0];
  const float* stem_w  = (const float*)d_in[1];
  const float* stem_b  = (const float*)d_in[2];
  const float* dw_w    = (const float*)d_in[3];
  const float* dw_b    = (const float*)d_in[4];
  const float* ln_g    = (const float*)d_in[5];
  const float* ln_b    = (const float*)d_in[6];
  const float* w1      = (const float*)d_in[7];
  const float* b1      = (const float*)d_in[8];
  const float* w2      = (const float*)d_in[9];
  const float* b2      = (const float*)d_in[10];
  const float* q_w     = (const float*)d_in[11];
  const float* kv_w    = (const float*)d_in[12];
  const float* out_w   = (const float*)d_in[13];
  const float* out_b   = (const float*)d_in[14];
  const float* latent  = (const float*)d_in[15];
  const float* lln_g   = (const float*)d_in[16];
  const float* lln_b   = (const float*)d_in[17];
  const float* head_w  = (const float*)d_in[18];
  const float* head_b  = (const float*)d_in[19];

  char* base = (char*)d_ws;
  size_t off = 0;
  auto alloc = [&](size_t bytes) {
    void* p = base + off;
    off += (bytes + 255) & ~(size_t)255;
    return p;
  };
  float* h     = (float*)alloc((size_t)T_ * DIM_ * 4);      // residual stream
  float* kvb   = (float*)alloc((size_t)T_ * 768 * 4);       // kv projections
  float* yb    = (float*)alloc((size_t)T_ * DIM_ * 4);      // dwconv+LN out
  float* hid   = (float*)alloc((size_t)T_ * HID_ * 4);      // MLP hidden (gelu'd)
  unsigned short* w1h = (unsigned short*)alloc((size_t)DEPTH_ * HID_ * DIM_ * 2);
  unsigned short* w1l = (unsigned short*)alloc((size_t)DEPTH_ * HID_ * DIM_ * 2);
  unsigned short* w2h = (unsigned short*)alloc((size_t)DEPTH_ * DIM_ * HID_ * 2);
  unsigned short* w2l = (unsigned short*)alloc((size_t)DEPTH_ * DIM_ * HID_ * 2);
  unsigned short* kvh = (unsigned short*)alloc((size_t)768 * DIM_ * 2);
  unsigned short* kvl = (unsigned short*)alloc((size_t)768 * DIM_ * 2);
  unsigned short* sth = (unsigned short*)alloc((size_t)DIM_ * KSTEM_ * 2);
  unsigned short* stl = (unsigned short*)alloc((size_t)DIM_ * KSTEM_ * 2);
  float* dwT   = (float*)alloc((size_t)DEPTH_ * 49 * DIM_ * 4);
  float* lat   = (float*)alloc((size_t)B_ * DIM_ * 4);
  float* patch = hid;   // T_*768*4 fits in T_*HID_*4; used only in prolog

  // ---- prep (all independent) ----
  im2col_stem<<<(T_ * KSTEM_ + 255) / 256, 256, 0, stream>>>(x, patch);
  split_only<<<(DIM_ * KSTEM_ + 255) / 256, 256, 0, stream>>>(stem_w, sth, stl, DIM_ * KSTEM_);
  tr_split_tiled<<<dim3(HID_ / 32, DIM_ / 32, DEPTH_), 256, 0, stream>>>(
      w1, w1h, w1l, DIM_, HID_);
  tr_split_tiled<<<dim3(DIM_ / 32, HID_ / 32, DEPTH_), 256, 0, stream>>>(
      w2, w2h, w2l, HID_, DIM_);
  tr_split_tiled<<<dim3(768 / 32, DIM_ / 32, 1), 256, 0, stream>>>(
      kv_w, kvh, kvl, DIM_, 768);
  tr_dw<<<(DEPTH_ * 49 * DIM_ + 255) / 256, 256, 0, stream>>>(dw_w, dwT);
  lat_init<<<(B_ * DIM_ + 255) / 256, 256, 0, stream>>>(latent, lat);

  // ---- stem: h = patch @ stemW^T + stem_b ----
  gemm2<128, 64, GEPI_BIAS><<<dim3(DIM_ / 64, T_ / 128), 256, 0, stream>>>(
      patch, sth, stl, h, stem_b, T_, DIM_, KSTEM_);

  // ---- kv for readout 0 ----
  gemm2<128, 128, GEPI_NONE><<<dim3(768 / 128, T_ / 128), 256, 0, stream>>>(
      h, kvh, kvl, kvb, nullptr, T_, 768, DIM_);

  // ---- blocks: [readout(l) || dwconv(l)] -> MLP1 -> MLP2(+resid) -> kv ----
  for (int l = 0; l < DEPTH_; ++l) {
    dwconv_readout<<<B_ + T_, 384, 0, stream>>>(
        h, dwT + (size_t)l * 49 * DIM_, dw_b + (size_t)l * DIM_,
        ln_g + (size_t)l * DIM_, ln_b + (size_t)l * DIM_, yb,
        kvb, lat, q_w, out_w, out_b, lln_g, lln_b);
    gemm2<128, 128, GEPI_GELU><<<dim3(HID_ / 128, T_ / 128), 256, 0, stream>>>(
        yb, w1h + (size_t)l * HID_ * DIM_, w1l + (size_t)l * HID_ * DIM_,
        hid, b1 + (size_t)l * HID_, T_, HID_, DIM_);
    gemm2<128, 64, GEPI_RESID><<<dim3(DIM_ / 64, T_ / 128), 256, 0, stream>>>(
        hid, w2h + (size_t)l * DIM_ * HID_, w2l + (size_t)l * DIM_ * HID_,
        h, b2 + (size_t)l * DIM_, T_, DIM_, HID_);
    gemm2<128, 128, GEPI_NONE><<<dim3(768 / 128, T_ / 128), 256, 0, stream>>>(
        h, kvh, kvl, kvb, nullptr, T_, 768, DIM_);
  }

  // final readout + head
  readout_attn<<<B_, 384, 0, stream>>>(kvb, lat, q_w, out_w, out_b, lln_g, lln_b);
  head_kernel<<<B_, 256, 0, stream>>>(lat, head_w, head_b, (float*)d_out);
}